// Round 7
// baseline (405.296 us; speedup 1.0000x reference)
//
#include <hip/hip_runtime.h>
#include <cstdint>
#include <cstddef>

#define DIM 128
#define BN_EPS 1e-5f
#define NS 8             // column-chunk shards (chunk = col >> 13)
#define CHUNK_SHIFT 13   // 8192 nodes/chunk * 256B = 2 MiB bf16, fits per-XCD L2
#define FIX_SCALE 16777216.0f  // 2^24

typedef short bf16x8 __attribute__((ext_vector_type(8)));
typedef float f32x4 __attribute__((ext_vector_type(4)));

__device__ __forceinline__ unsigned short f2bf(float f) {
  unsigned u = __float_as_uint(f);
  u = (u + 0x7fffu + ((u >> 16) & 1u)) >> 16;
  return (unsigned short)u;
}
__device__ __forceinline__ float bf2f(unsigned v) {  // low 16 bits
  return __uint_as_float(v << 16);
}

// ---------------- preprocessing ----------------

// One packed u64 atomic per edge into shard g = chunk(col): high32 = count,
// low32 = sum of fix24(ew). Returned old high word = edge's rank within its
// (row, colchunk) segment -> atomic-free scatter later.
__global__ void deg_hist_kernel(const int* __restrict__ ei, const float* __restrict__ ew,
                                unsigned long long* __restrict__ pck,
                                unsigned* __restrict__ eidx, int E, int N) {
  int e = blockIdx.x * blockDim.x + threadIdx.x;
  if (e < E) {
    int r = ei[e];
    int g = ei[E + e] >> CHUNK_SHIFT;
    unsigned fix = (unsigned)(ew[e] * FIX_SCALE + 0.5f);
    unsigned long long old =
        atomicAdd(&pck[(size_t)g * N + r], (1ull << 32) | (unsigned long long)fix);
    eidx[e] = (unsigned)(old >> 32);
  }
}

// deg = (sum over shards of low32) * 2^-24 ; dinv = rsqrt
__global__ void reduce_dinv_kernel(const unsigned long long* __restrict__ pck,
                                   float* __restrict__ dinv, int N) {
  int i = blockIdx.x * blockDim.x + threadIdx.x;
  if (i < N) {
    float d = 0.f;
#pragma unroll
    for (int g = 0; g < NS; ++g)
      d += (float)(unsigned)(pck[(size_t)g * N + i] & 0xffffffffull);
    d *= (1.0f / FIX_SCALE);
    dinv[i] = d > 0.f ? rsqrtf(fmaxf(d, 1e-30f)) : 0.f;
  }
}

// scan over 8N counts (row-major, chunk-minor) -> off2[r*8+g]
// => per-row edge segments ordered by column chunk (cache-blocked SpMM).
__global__ __launch_bounds__(512) void scan_a_kernel(const unsigned long long* __restrict__ pck,
                                                     int* __restrict__ off2,
                                                     int* __restrict__ bsums, int n8, int N) {
  __shared__ int sd[512];
  int t = threadIdx.x;
  int i = blockIdx.x * 512 + t;
  int v = 0;
  if (i < n8) {
    int g = i & (NS - 1), r = i >> 3;
    v = (int)(pck[(size_t)g * N + r] >> 32);
  }
  sd[t] = v;
  __syncthreads();
  for (int off = 1; off < 512; off <<= 1) {
    int x = (t >= off) ? sd[t - off] : 0;
    __syncthreads();
    sd[t] += x;
    __syncthreads();
  }
  if (i < n8) off2[i] = sd[t] - v;
  if (t == 511) bsums[blockIdx.x] = sd[511];
}

__global__ __launch_bounds__(1024) void scan_b_kernel(int* __restrict__ bsums, int nb) {
  __shared__ int sd[1024];
  int t = threadIdx.x;
  int v = (t < nb) ? bsums[t] : 0;
  sd[t] = v;
  __syncthreads();
  for (int off = 1; off < 1024; off <<= 1) {
    int x = (t >= off) ? sd[t - off] : 0;
    __syncthreads();
    sd[t] += x;
    __syncthreads();
  }
  if (t < nb) bsums[t] = sd[t] - v;  // exclusive
}

// add block offsets; also emit row_ptr (every 8th element) and row_ptr[N]=E
__global__ __launch_bounds__(512) void scan_c_kernel(int* __restrict__ off2,
                                                     const int* __restrict__ bsums,
                                                     int* __restrict__ row_ptr, int n8, int N,
                                                     int E) {
  int i = blockIdx.x * 512 + threadIdx.x;
  if (i < n8) {
    int v = off2[i] + bsums[blockIdx.x];
    off2[i] = v;
    if ((i & (NS - 1)) == 0) row_ptr[i >> 3] = v;
  }
  if (blockIdx.x == 0 && threadIdx.x == 0) row_ptr[N] = E;
}

// atomic-free scatter: pos = off2[r*8+chunk(c)] + eidx[e]
__global__ void scatter_kernel(const int* __restrict__ ei, const float* __restrict__ ew,
                               const float* __restrict__ dinv, const int* __restrict__ off2,
                               const unsigned* __restrict__ eidx, int2* __restrict__ cw, int E,
                               int N) {
  int e = blockIdx.x * blockDim.x + threadIdx.x;
  if (e < E) {
    int r = ei[e], c = ei[E + e];
    int g = c >> CHUNK_SHIFT;
    float w = -dinv[r] * ew[e] * dinv[c];
    int pos = off2[r * NS + g] + (int)eidx[e];
    cw[pos] = make_int2(c, __float_as_int(w));
  }
}

// ---------------- weight prep ----------------

// WcatT[o][k] bf16, k = seg*128 + i ; seg0 = W0-W2, seg1 = W1, seg2 = 2*W2; blockIdx.y = layer
__global__ void combine_weightsT_kernel(const float* __restrict__ W0,
                                        const float* __restrict__ W1,
                                        const float* __restrict__ W2,
                                        unsigned short* __restrict__ WcatT) {
  int l = blockIdx.y;
  const float* W = (l == 0) ? W0 : (l == 1) ? W1 : W2;
  unsigned short* outp = WcatT + (size_t)l * 128 * 384;
  int idx = blockIdx.x * blockDim.x + threadIdx.x;
  if (idx < DIM * DIM) {
    int i = idx >> 7, o = idx & 127;
    float w0 = W[i * DIM + o];
    float w1 = W[DIM * DIM + i * DIM + o];
    float w2 = W[2 * DIM * DIM + i * DIM + o];
    outp[(size_t)o * 384 + i] = f2bf(w0 - w2);
    outp[(size_t)o * 384 + 128 + i] = f2bf(w1);
    outp[(size_t)o * 384 + 256 + i] = f2bf(2.0f * w2);
  }
}

__global__ void wc1t_kernel(const float* __restrict__ Wc1, unsigned short* __restrict__ Wc1T) {
  int idx = blockIdx.x * blockDim.x + threadIdx.x;
  if (idx < 128 * 256) {
    int k = idx >> 8, n = idx & 255;
    Wc1T[(size_t)n * 128 + k] = f2bf(Wc1[(size_t)k * 256 + n]);
  }
}

__global__ void f2bf_kernel(const float* __restrict__ in, unsigned short* __restrict__ outp,
                            int n4) {
  int i = blockIdx.x * blockDim.x + threadIdx.x;
  if (i < n4) {
    float4 v = reinterpret_cast<const float4*>(in)[i];
    ushort4 o;
    o.x = f2bf(v.x); o.y = f2bf(v.y); o.z = f2bf(v.z); o.w = f2bf(v.w);
    reinterpret_cast<ushort4*>(outp)[i] = o;
  }
}

// ---------------- SpMM: Y = L_hat @ X (bf16, fp32 accum) ----------------
// Wave = 1 row; lane halves process even/odd edges; lane covers 4 cols (uint2 = 8B).
// Edges are column-chunk sorted per row -> concurrent waves share a ~2MiB
// gather working set that fits per-XCD L2.

__global__ __launch_bounds__(256) void spmm_kernel(const int* __restrict__ row_ptr,
                                                   const int2* __restrict__ cw,
                                                   const unsigned short* __restrict__ X,
                                                   unsigned short* __restrict__ Y, int N) {
  int row = (blockIdx.x * blockDim.x + threadIdx.x) >> 6;
  int lane = threadIdx.x & 63;
  if (row >= N) return;
  int half = lane >> 5;
  int l32 = lane & 31;
  int cb = l32 * 4;
  int s = row_ptr[row], e = row_ptr[row + 1];
  float a0 = 0.f, a1 = 0.f, a2 = 0.f, a3 = 0.f;
  float b0 = 0.f, b1 = 0.f, b2 = 0.f, b3 = 0.f;
  int j = s + half;
  for (; j + 6 < e; j += 8) {
    int2 e0 = cw[j], e1 = cw[j + 2], e2 = cw[j + 4], e3 = cw[j + 6];
    uint2 v0 = *reinterpret_cast<const uint2*>(X + (size_t)e0.x * DIM + cb);
    uint2 v1 = *reinterpret_cast<const uint2*>(X + (size_t)e1.x * DIM + cb);
    uint2 v2 = *reinterpret_cast<const uint2*>(X + (size_t)e2.x * DIM + cb);
    uint2 v3 = *reinterpret_cast<const uint2*>(X + (size_t)e3.x * DIM + cb);
    float w0 = __int_as_float(e0.y), w1 = __int_as_float(e1.y);
    float w2 = __int_as_float(e2.y), w3 = __int_as_float(e3.y);
    a0 += w0 * bf2f(v0.x & 0xffffu); a1 += w0 * bf2f(v0.x >> 16);
    a2 += w0 * bf2f(v0.y & 0xffffu); a3 += w0 * bf2f(v0.y >> 16);
    b0 += w1 * bf2f(v1.x & 0xffffu); b1 += w1 * bf2f(v1.x >> 16);
    b2 += w1 * bf2f(v1.y & 0xffffu); b3 += w1 * bf2f(v1.y >> 16);
    a0 += w2 * bf2f(v2.x & 0xffffu); a1 += w2 * bf2f(v2.x >> 16);
    a2 += w2 * bf2f(v2.y & 0xffffu); a3 += w2 * bf2f(v2.y >> 16);
    b0 += w3 * bf2f(v3.x & 0xffffu); b1 += w3 * bf2f(v3.x >> 16);
    b2 += w3 * bf2f(v3.y & 0xffffu); b3 += w3 * bf2f(v3.y >> 16);
  }
  for (; j < e; j += 2) {
    int2 e0 = cw[j];
    uint2 v0 = *reinterpret_cast<const uint2*>(X + (size_t)e0.x * DIM + cb);
    float w0 = __int_as_float(e0.y);
    a0 += w0 * bf2f(v0.x & 0xffffu); a1 += w0 * bf2f(v0.x >> 16);
    a2 += w0 * bf2f(v0.y & 0xffffu); a3 += w0 * bf2f(v0.y >> 16);
  }
  a0 += b0; a1 += b1; a2 += b2; a3 += b3;
  a0 += __shfl_xor(a0, 32);
  a1 += __shfl_xor(a1, 32);
  a2 += __shfl_xor(a2, 32);
  a3 += __shfl_xor(a3, 32);
  if (half == 0) {
    uint2 o;
    o.x = (unsigned)f2bf(a0) | ((unsigned)f2bf(a1) << 16);
    o.y = (unsigned)f2bf(a2) | ((unsigned)f2bf(a3) << 16);
    *reinterpret_cast<uint2*>(Y + (size_t)row * DIM + cb) = o;
  }
}

// ---------------- layer GEMM (MFMA): out = relu(X@(W0-W2) + S1@W1 + S2@(2W2)) ----------------

__global__ __launch_bounds__(256) void gemm3_mfma_kernel(const unsigned short* __restrict__ X,
                                                         const unsigned short* __restrict__ S1,
                                                         const unsigned short* __restrict__ S2,
                                                         const unsigned short* __restrict__ BT,
                                                         unsigned short* __restrict__ out, int M) {
  __shared__ short As[128 * 40];
  __shared__ short Bs[128 * 40];
  int tid = threadIdx.x;
  int wv = tid >> 6, ln = tid & 63;
  int lg = ln >> 4, lr = ln & 15;
  int blockRow = blockIdx.x * 128;
  f32x4 acc[2][8];
#pragma unroll
  for (int m = 0; m < 2; ++m)
#pragma unroll
    for (int n = 0; n < 8; ++n) acc[m][n] = (f32x4){0.f, 0.f, 0.f, 0.f};
  const unsigned short* srcs[3] = {X, S1, S2};
  int srow = tid >> 1;
  int scol = (tid & 1) * 16;
  int arow = blockRow + srow;
  bool aok = arow < M;
  for (int seg = 0; seg < 3; ++seg) {
    const unsigned short* src = srcs[seg];
    for (int k0 = 0; k0 < DIM; k0 += 32) {
      float4 av0, av1;
      if (aok) {
        const float4* ap = reinterpret_cast<const float4*>(src + (size_t)arow * DIM + k0 + scol);
        av0 = ap[0];
        av1 = ap[1];
      } else {
        av0 = make_float4(0.f, 0.f, 0.f, 0.f);
        av1 = av0;
      }
      const float4* bp =
          reinterpret_cast<const float4*>(BT + (size_t)srow * 384 + seg * DIM + k0 + scol);
      float4 bv0 = bp[0], bv1 = bp[1];
      __syncthreads();
      *reinterpret_cast<float4*>(&As[srow * 40 + scol]) = av0;
      *reinterpret_cast<float4*>(&As[srow * 40 + scol + 8]) = av1;
      *reinterpret_cast<float4*>(&Bs[srow * 40 + scol]) = bv0;
      *reinterpret_cast<float4*>(&Bs[srow * 40 + scol + 8]) = bv1;
      __syncthreads();
      bf16x8 af[2], bf[8];
#pragma unroll
      for (int m = 0; m < 2; ++m)
        af[m] = *reinterpret_cast<const bf16x8*>(&As[(wv * 32 + m * 16 + lr) * 40 + lg * 8]);
#pragma unroll
      for (int n = 0; n < 8; ++n)
        bf[n] = *reinterpret_cast<const bf16x8*>(&Bs[(n * 16 + lr) * 40 + lg * 8]);
#pragma unroll
      for (int m = 0; m < 2; ++m)
#pragma unroll
        for (int n = 0; n < 8; ++n)
          acc[m][n] = __builtin_amdgcn_mfma_f32_16x16x32_bf16(af[m], bf[n], acc[m][n], 0, 0, 0);
    }
  }
#pragma unroll
  for (int m = 0; m < 2; ++m)
#pragma unroll
    for (int n = 0; n < 8; ++n) {
      int col = n * 16 + lr;
#pragma unroll
      for (int r = 0; r < 4; ++r) {
        int grow = blockRow + wv * 32 + m * 16 + lg * 4 + r;
        if (grow < M) out[(size_t)grow * DIM + col] = f2bf(fmaxf(acc[m][n][r], 0.f));
      }
    }
}

// ---------------- head GEMM (MFMA): h = relu(X@Wc1 + bc1), bf16 out + fused BN stats ----------------

__global__ __launch_bounds__(256) void head_mfma_kernel(const unsigned short* __restrict__ X,
                                                        const unsigned short* __restrict__ BT,
                                                        const float* __restrict__ bc1,
                                                        unsigned short* __restrict__ h,
                                                        float* __restrict__ sums, int M) {
  __shared__ short As[128 * 40];
  __shared__ short Bs[128 * 40];
  int tid = threadIdx.x;
  int wv = tid >> 6, ln = tid & 63;
  int lg = ln >> 4, lr = ln & 15;
  int blockRow = blockIdx.x * 128;
  int n0 = blockIdx.y * 128;
  f32x4 acc[2][8];
#pragma unroll
  for (int m = 0; m < 2; ++m)
#pragma unroll
    for (int n = 0; n < 8; ++n) acc[m][n] = (f32x4){0.f, 0.f, 0.f, 0.f};
  int srow = tid >> 1;
  int scol = (tid & 1) * 16;
  int arow = blockRow + srow;
  bool aok = arow < M;
  for (int k0 = 0; k0 < DIM; k0 += 32) {
    float4 av0, av1;
    if (aok) {
      const float4* ap = reinterpret_cast<const float4*>(X + (size_t)arow * DIM + k0 + scol);
      av0 = ap[0];
      av1 = ap[1];
    } else {
      av0 = make_float4(0.f, 0.f, 0.f, 0.f);
      av1 = av0;
    }
    const float4* bp =
        reinterpret_cast<const float4*>(BT + (size_t)(n0 + srow) * DIM + k0 + scol);
    float4 bv0 = bp[0], bv1 = bp[1];
    __syncthreads();
    *reinterpret_cast<float4*>(&As[srow * 40 + scol]) = av0;
    *reinterpret_cast<float4*>(&As[srow * 40 + scol + 8]) = av1;
    *reinterpret_cast<float4*>(&Bs[srow * 40 + scol]) = bv0;
    *reinterpret_cast<float4*>(&Bs[srow * 40 + scol + 8]) = bv1;
    __syncthreads();
    bf16x8 af[2], bf[8];
#pragma unroll
    for (int m = 0; m < 2; ++m)
      af[m] = *reinterpret_cast<const bf16x8*>(&As[(wv * 32 + m * 16 + lr) * 40 + lg * 8]);
#pragma unroll
    for (int n = 0; n < 8; ++n)
      bf[n] = *reinterpret_cast<const bf16x8*>(&Bs[(n * 16 + lr) * 40 + lg * 8]);
#pragma unroll
    for (int m = 0; m < 2; ++m)
#pragma unroll
      for (int n = 0; n < 8; ++n)
        acc[m][n] = __builtin_amdgcn_mfma_f32_16x16x32_bf16(af[m], bf[n], acc[m][n], 0, 0, 0);
  }
  float psum[8], psq[8];
#pragma unroll
  for (int n = 0; n < 8; ++n) { psum[n] = 0.f; psq[n] = 0.f; }
#pragma unroll
  for (int m = 0; m < 2; ++m)
#pragma unroll
    for (int n = 0; n < 8; ++n) {
      int colg = n0 + n * 16 + lr;
      float bias = bc1[colg];
#pragma unroll
      for (int r = 0; r < 4; ++r) {
        int grow = blockRow + wv * 32 + m * 16 + lg * 4 + r;
        if (grow < M) {
          float v = fmaxf(acc[m][n][r] + bias, 0.f);
          h[(size_t)grow * 256 + colg] = f2bf(v);
          psum[n] += v;
          psq[n] += v * v;
        }
      }
    }
  float* Rs = reinterpret_cast<float*>(As);
  int rid = wv * 4 + lg;
  __syncthreads();
#pragma unroll
  for (int n = 0; n < 8; ++n) Rs[rid * 128 + n * 16 + lr] = psum[n];
  __syncthreads();
  if (tid < 128) {
    float s = 0.f;
#pragma unroll
    for (int r = 0; r < 16; ++r) s += Rs[r * 128 + tid];
    atomicAdd(&sums[n0 + tid], s);
  }
  __syncthreads();
#pragma unroll
  for (int n = 0; n < 8; ++n) Rs[rid * 128 + n * 16 + lr] = psq[n];
  __syncthreads();
  if (tid < 128) {
    float s = 0.f;
#pragma unroll
    for (int r = 0; r < 16; ++r) s += Rs[r * 128 + tid];
    atomicAdd(&sums[256 + n0 + tid], s);
  }
}

__global__ __launch_bounds__(256) void bnfold_kernel(const float* __restrict__ sums,
                                                     const float* __restrict__ gamma,
                                                     const float* __restrict__ beta,
                                                     const float* __restrict__ Wc2,
                                                     const float* __restrict__ bc2,
                                                     float* __restrict__ W2e,
                                                     float* __restrict__ b2e, int M) {
  __shared__ float bsh[256];
  int c = threadIdx.x;
  float mean = sums[c] / (float)M;
  float var = sums[256 + c] / (float)M - mean * mean;
  float a = gamma[c] * rsqrtf(var + BN_EPS);
  float b = beta[c] - mean * a;
  for (int j = 0; j < 10; ++j) W2e[c * 10 + j] = a * Wc2[c * 10 + j];
  bsh[c] = b;
  __syncthreads();
  if (c < 10) {
    float t = bc2[c];
    for (int k = 0; k < 256; ++k) t += bsh[k] * Wc2[k * 10 + c];
    b2e[c] = t;
  }
}

// ---------------- final: logit = h @ W2e + b2e (thread per row, broadcast W) ----------------

__global__ __launch_bounds__(256) void final_kernel(const unsigned short* __restrict__ h,
                                                    const float* __restrict__ W2e,
                                                    const float* __restrict__ b2e,
                                                    float* __restrict__ out, int M) {
  __shared__ float Ws[2560];
  __shared__ float bs[16];
  for (int i = threadIdx.x; i < 2560; i += 256) Ws[i] = W2e[i];
  if (threadIdx.x < 10) bs[threadIdx.x] = b2e[threadIdx.x];
  __syncthreads();
  int row = blockIdx.x * 256 + threadIdx.x;
  if (row >= M) return;
  float p[10];
#pragma unroll
  for (int j = 0; j < 10; ++j) p[j] = bs[j];
  const uint4* hp = reinterpret_cast<const uint4*>(h + (size_t)row * 256);
#pragma unroll 4
  for (int k0 = 0; k0 < 32; ++k0) {
    uint4 v = hp[k0];
    unsigned vv[4] = {v.x, v.y, v.z, v.w};
#pragma unroll
    for (int t = 0; t < 4; ++t) {
      float f0 = bf2f(vv[t] & 0xffffu);
      float f1 = bf2f(vv[t] >> 16);
      const float* w0 = &Ws[(k0 * 8 + t * 2) * 10];  // uniform address -> LDS broadcast
#pragma unroll
      for (int j = 0; j < 10; ++j) p[j] += f0 * w0[j] + f1 * w0[10 + j];
    }
  }
#pragma unroll
  for (int j = 0; j < 10; ++j) out[(size_t)row * 10 + j] = p[j];
}

__global__ void copy4_kernel(const float* __restrict__ src, float* __restrict__ dst, int n) {
  int i = blockIdx.x * blockDim.x + threadIdx.x;
  int i4 = i * 4;
  if (i4 + 3 < n) {
    reinterpret_cast<float4*>(dst)[i] = reinterpret_cast<const float4*>(src)[i];
  } else {
    for (int k = i4; k < n; ++k) dst[k] = src[k];
  }
}

// ---------------- launch ----------------

extern "C" void kernel_launch(void* const* d_in, const int* in_sizes, int n_in,
                              void* d_out, int out_size, void* d_ws, size_t ws_size,
                              hipStream_t stream) {
  const float* features = (const float*)d_in[0];
  const int* ei = (const int*)d_in[1];
  const float* ew = (const float*)d_in[2];
  const float* W0 = (const float*)d_in[3];
  const float* W1 = (const float*)d_in[4];
  const float* W2 = (const float*)d_in[5];
  const float* Wc1 = (const float*)d_in[6];
  const float* bc1 = (const float*)d_in[7];
  const float* gamma = (const float*)d_in[8];
  const float* beta = (const float*)d_in[9];
  const float* Wc2 = (const float*)d_in[10];
  const float* bc2 = (const float*)d_in[11];
  float* out = (float*)d_out;

  const int N = in_sizes[0] / DIM;
  const int E = in_sizes[2];
  const int n8 = N * NS;

  size_t off = 0;
  auto alloc = [&](size_t bytes) -> void* {
    void* p = (char*)d_ws + off;
    off += (bytes + 511) & ~(size_t)511;
    return p;
  };
  float* dinv = (float*)alloc((size_t)N * 4);
  unsigned long long* pck = (unsigned long long*)alloc((size_t)n8 * 8);
  unsigned* eidx = (unsigned*)alloc((size_t)E * 4);
  int* off2 = (int*)alloc((size_t)(n8 + NS) * 4);
  int* bsums = (int*)alloc(1024 * 4);
  int* row_ptr = (int*)alloc((size_t)(N + 1) * 4);
  int2* cw = (int2*)alloc((size_t)E * 8);
  unsigned short* featbf = (unsigned short*)alloc((size_t)N * DIM * 2);
  unsigned short* xbuf = (unsigned short*)alloc((size_t)N * DIM * 2);
  unsigned short* S1 = (unsigned short*)alloc((size_t)N * DIM * 2);
  unsigned short* S2 = (unsigned short*)alloc((size_t)N * DIM * 2);
  unsigned short* h = (unsigned short*)alloc((size_t)N * 256 * 2);
  unsigned short* WcatT = (unsigned short*)alloc((size_t)3 * 128 * 384 * 2);
  unsigned short* Wc1T = (unsigned short*)alloc((size_t)256 * 128 * 2);
  float* W2e = (float*)alloc(2560 * 4);
  float* b2e = (float*)alloc(16 * 4);
  float* sums = (float*)alloc(512 * 4);

  hipMemsetAsync(pck, 0, (size_t)n8 * 8, stream);
  hipMemsetAsync(sums, 0, 512 * 4, stream);

  int eb = (E + 255) / 256;
  int nb = (N + 255) / 256;
  int sa_blocks = (n8 + 511) / 512;

  f2bf_kernel<<<(N * DIM / 4 + 255) / 256, 256, 0, stream>>>(features, featbf, N * DIM / 4);
  deg_hist_kernel<<<eb, 256, 0, stream>>>(ei, ew, pck, eidx, E, N);
  reduce_dinv_kernel<<<nb, 256, 0, stream>>>(pck, dinv, N);
  scan_a_kernel<<<sa_blocks, 512, 0, stream>>>(pck, off2, bsums, n8, N);
  scan_b_kernel<<<1, 1024, 0, stream>>>(bsums, sa_blocks);
  scan_c_kernel<<<sa_blocks, 512, 0, stream>>>(off2, bsums, row_ptr, n8, N, E);
  scatter_kernel<<<eb, 256, 0, stream>>>(ei, ew, dinv, off2, eidx, cw, E, N);

  dim3 cwgrid((DIM * DIM + 255) / 256, 3);
  combine_weightsT_kernel<<<cwgrid, 256, 0, stream>>>(W0, W1, W2, WcatT);
  wc1t_kernel<<<(128 * 256 + 255) / 256, 256, 0, stream>>>(Wc1, Wc1T);

  int spmm_blocks = (N + 3) / 4;
  int gemm_blocks = (N + 127) / 128;
  for (int l = 0; l < 3; ++l) {
    const unsigned short* X = (l == 0) ? featbf : xbuf;
    spmm_kernel<<<spmm_blocks, 256, 0, stream>>>(row_ptr, cw, X, S1, N);
    spmm_kernel<<<spmm_blocks, 256, 0, stream>>>(row_ptr, cw, S1, S2, N);
    gemm3_mfma_kernel<<<gemm_blocks, 256, 0, stream>>>(X, S1, S2, WcatT + (size_t)l * 128 * 384,
                                                       xbuf, N);
  }

  dim3 hgrid(gemm_blocks, 2);
  head_mfma_kernel<<<hgrid, 256, 0, stream>>>(xbuf, Wc1T, bc1, h, sums, N);
  bnfold_kernel<<<1, 256, 0, stream>>>(sums, gamma, beta, Wc2, bc2, W2e, b2e, N);
  final_kernel<<<(N + 255) / 256, 256, 0, stream>>>(h, W2e, b2e, out, N);
  copy4_kernel<<<(E / 4 + 255) / 256, 256, 0, stream>>>(ew, out + (size_t)N * 10, E);
}